// Round 13
// baseline (863.448 us; speedup 1.0000x reference)
//
#include <hip/hip_runtime.h>

// 4-layer LSTM (15/20/30/40), B=8192, T=512, fp32 in/out. MFMA split-bf16,
// layer-pipelined: period P runs L1@t=P, L2@P-1, L3@P-2, L4@P-3, y@P-4.
// 1024 threads = 16 waves, ONE tile per wave (14 tiles + y + x), 4 waves/SIMD,
// one barrier per period, h stored once per parity.
// r13 = EXACT r7 (fastest PASS, 786us) + ONE delta: the 3 split-bf16 MFMA
// terms accumulate into THREE independent accumulators (chain depth 15 -> 5,
// ~-300 cyc dependent latency on the pace-setting L4 waves) summed in the
// epilogue. r11 prefetch / r12 shared-denominator reverted (both neutral-to-
// negative; r12 proved the period is chain-bound, not issue-bound).

#define NT 1024
#define TS 512

typedef __attribute__((ext_vector_type(8)))  short short8v;
typedef __attribute__((ext_vector_type(16))) float f32x16;

// LDS (ushort units): 4 planes [parity(2) x hi/lo] of 3840:
//   region offsets within a plane: SX=0(1 slot) H1=256(2) H2=768(3)
//   H3=1536(4) H4=2560(5); slot = 256 ush = 32 elem x 8 k.
// plane(par,q) base = par*7680 + q*3840. Shared tail: ONE@15360 (0x3F80),
// Z@15616, and [19200,19712) zeros so ptr+3840 of ONE/Z reads zeros.
#define RH1 256
#define RH2 768
#define RH3 1536
#define RH4 2560
#define ONEO 15360
#define ZO   15616
#define STOTU 19712

__device__ __forceinline__ float fexp2(float x){ float r; asm("v_exp_f32 %0, %1" : "=v"(r) : "v"(x)); return r; }
__device__ __forceinline__ float frcp(float x){ float r; asm("v_rcp_f32 %0, %1" : "=v"(r) : "v"(x)); return r; }
#define LOG2E 1.4426950408889634f
__device__ __forceinline__ float sigm(float x)  { return frcp(1.0f + fexp2(-LOG2E * x)); }
__device__ __forceinline__ float tanhp(float x) { return 1.0f - 2.0f * frcp(1.0f + fexp2((2.0f*LOG2E) * x)); }

__device__ __forceinline__ unsigned cvtpk(float a, float b){
  unsigned r; asm("v_cvt_pk_bf16_f32 %0, %1, %2" : "=v"(r) : "v"(a), "v"(b)); return r;
}
__device__ __forceinline__ unsigned short bfr(float f){
  unsigned u = __float_as_uint(f);
  u += 0x7FFFu + ((u >> 16) & 1u);
  return (unsigned short)(u >> 16);
}
__device__ __forceinline__ float bfv(unsigned short s){
  return __uint_as_float(((unsigned)s) << 16);
}

// Gather one 32-row M-tile of split-bf16 A-fragments from global fp32.
// A-row m: gate g=m&3, unit u = 8*mt + 4*((m>>2)&1) + (m>>3) -> lane's C regs
// q=4r+g cover consecutive units u0t+4*up .. +3.
// k map: k<DIN: Wih; k==BIASK: bih+bhh; H0<=k<H0+DL: Whh[k-H0]; else 0.
template<int KT>
__device__ void gatherA(short8v (&ah)[5], short8v (&al)[5], int lane, int mt,
                        const float* Wih, const float* Whh,
                        const float* bih, const float* bhh,
                        int DL, int DIN, int BIASK, int H0) {
  const int upg = lane >> 5, rl = lane & 31;
  const int g = rl & 3;
  const int u = 8*mt + 4*((rl >> 2) & 1) + (rl >> 3);
#pragma unroll
  for (int kt = 0; kt < KT; ++kt) {
#pragma unroll
    for (int j = 0; j < 8; ++j) {
      const int k = kt*16 + upg*8 + j;
      float v = 0.0f;
      if (u < DL) {
        const int srow = g*DL + u;
        if (k < DIN)                      v = Wih[srow*DIN + k];
        else if (k == BIASK)              v = bih[srow] + bhh[srow];
        else if (k >= H0 && k < H0 + DL)  v = Whh[srow*DL + (k - H0)];
      }
      const unsigned short hi = bfr(v);
      const unsigned short lo = bfr(v - bfv(hi));
      ah[kt][j] = (short)hi;
      al[kt][j] = (short)lo;
    }
  }
}

// One tile: B-frag reads via precomputed slot pointers (lo plane = +3840),
// 3 INDEPENDENT accumulators (Ah*Bh / Ah*Bl / Al*Bh) summed in the epilogue
// -> MFMA dependent-chain depth KT instead of 3*KT. Lane-local cell update,
// b64 hi/lo h write at wr.
template<int KT>
__device__ __forceinline__ void doTile(
    const short8v (&ah)[5], const short8v (&al)[5],
    const unsigned short* const (&bp)[KT],
    float (&cst)[4], unsigned short* wr, float* scrp) {
  short8v Bh[KT], Bl[KT];
#pragma unroll
  for (int kt = 0; kt < KT; ++kt) {
    Bh[kt] = *(const short8v*)(bp[kt]);
    Bl[kt] = *(const short8v*)(bp[kt] + 3840);
  }
  f32x16 a1 = {}, a2 = {}, a3 = {};
#pragma unroll
  for (int kt = 0; kt < KT; ++kt)
    a1 = __builtin_amdgcn_mfma_f32_32x32x16_bf16(ah[kt], Bh[kt], a1, 0, 0, 0);
#pragma unroll
  for (int kt = 0; kt < KT; ++kt)
    a2 = __builtin_amdgcn_mfma_f32_32x32x16_bf16(ah[kt], Bl[kt], a2, 0, 0, 0);
#pragma unroll
  for (int kt = 0; kt < KT; ++kt)
    a3 = __builtin_amdgcn_mfma_f32_32x32x16_bf16(al[kt], Bh[kt], a3, 0, 0, 0);
  // C layout: col = lane&31 = element n, row = (q&3)+8*(q>>2)+4*up
  float h[4];
#pragma unroll
  for (int r = 0; r < 4; ++r) {
    const float gi = a1[4*r+0] + a2[4*r+0] + a3[4*r+0];
    const float gf = a1[4*r+1] + a2[4*r+1] + a3[4*r+1];
    const float gg = a1[4*r+2] + a2[4*r+2] + a3[4*r+2];
    const float go = a1[4*r+3] + a2[4*r+3] + a3[4*r+3];
    const float ii = sigm(gi);
    const float ff = sigm(gf);
    const float g2 = tanhp(gg);
    const float oo = sigm(go);
    cst[r] = fmaf(ff, cst[r], ii * g2);
    h[r] = oo * tanhp(cst[r]);
  }
  const unsigned pa = cvtpk(h[0], h[1]);
  const unsigned pb = cvtpk(h[2], h[3]);
  const float f0 = h[0] - __uint_as_float(pa << 16);
  const float f1 = h[1] - __uint_as_float(pa & 0xFFFF0000u);
  const float f2 = h[2] - __uint_as_float(pb << 16);
  const float f3 = h[3] - __uint_as_float(pb & 0xFFFF0000u);
  uint2 vh; vh.x = pa;            vh.y = pb;
  uint2 vl; vl.x = cvtpk(f0, f1); vl.y = cvtpk(f2, f3);
  *(uint2*)wr = vh;
  *(uint2*)(wr + 3840) = vl;
  if (scrp) *(float4*)scrp = make_float4(h[0], h[1], h[2], h[3]);
}

// x staging into SX slot: elem el, half -> k = half*4+j (half1: x4,x5,x6,1.0)
__device__ __forceinline__ void writeX(unsigned short* plane, int el, int half,
                                       float v0, float v1, float v2, float v3) {
  const unsigned pa = cvtpk(v0, v1), pb = cvtpk(v2, v3);
  const float f0 = v0 - __uint_as_float(pa << 16);
  const float f1 = v1 - __uint_as_float(pa & 0xFFFF0000u);
  const float f2 = v2 - __uint_as_float(pb << 16);
  const float f3 = v3 - __uint_as_float(pb & 0xFFFF0000u);
  uint2 vh; vh.x = pa;            vh.y = pb;
  uint2 vl; vl.x = cvtpk(f0, f1); vl.y = cvtpk(f2, f3);
  const int a = (el << 3) + (half << 2);
  *(uint2*)(plane + a) = vh;
  *(uint2*)(plane + a + 3840) = vl;
}

__global__ void __launch_bounds__(NT, 4)
lstm_pipe16(const float* __restrict__ x,
            const float* __restrict__ Wih1, const float* __restrict__ Whh1,
            const float* __restrict__ bih1, const float* __restrict__ bhh1,
            const float* __restrict__ Wih2, const float* __restrict__ Whh2,
            const float* __restrict__ bih2, const float* __restrict__ bhh2,
            const float* __restrict__ Wih3, const float* __restrict__ Whh3,
            const float* __restrict__ bih3, const float* __restrict__ bhh3,
            const float* __restrict__ Wih4, const float* __restrict__ Whh4,
            const float* __restrict__ bih4, const float* __restrict__ bhh4,
            const float* __restrict__ Wl, const float* __restrict__ bl,
            float* __restrict__ out) {
  __shared__ __align__(16) unsigned short S[STOTU];
  __shared__ __align__(16) float scrA[2*32*44];
  __shared__ __align__(16) float obuf[32*68];
  __shared__ float wlS[41];

  const int tid  = threadIdx.x;
  const int wv   = tid >> 6, lane = tid & 63;
  const int n    = lane & 31, up = lane >> 5;
  const int n8   = n << 3;
  const long gb  = (long)blockIdx.x * 32;

  for (int i = tid; i < STOTU/2; i += NT) ((unsigned*)S)[i] = 0u;
  if (tid < 41) wlS[tid] = (tid < 40) ? Wl[tid] : bl[0];
  __syncthreads();
  if (tid < 256) S[ONEO + tid] = 0x3F80;   // shared ones slot (hi only)
  // x(0) -> parity 0 SX (wv15)
  if (wv == 15) {
    const int el = lane >> 1, half = lane & 1;
    const float* xa = x + (gb + el)*(TS*7) + (half << 2);
    writeX(S + 0, el, half, xa[0], xa[1], xa[2], half ? 1.0f : xa[3]);
  }

  // ---- one-time A-frag gather; role table (SIMD-balanced by wv&3) ----
  // wv: 0=L1m0 1=L1m1 2=L2m2 3=L3m3 4=L2m0 5=L2m1 6=L3m2 7=L4m3
  //     8=L4m0 9=L4m1 10=L4m2 11=L4m4 12=L3m0 13=L3m1 14=y 15=x
  short8v ah[5], al[5];
  if      (wv == 0)  gatherA<2>(ah,al,lane,0,Wih1,Whh1,bih1,bhh1,15,7,7,8);
  else if (wv == 1)  gatherA<2>(ah,al,lane,1,Wih1,Whh1,bih1,bhh1,15,7,7,8);
  else if (wv == 4)  gatherA<3>(ah,al,lane,0,Wih2,Whh2,bih2,bhh2,20,15,16,24);
  else if (wv == 5)  gatherA<3>(ah,al,lane,1,Wih2,Whh2,bih2,bhh2,20,15,16,24);
  else if (wv == 2)  gatherA<3>(ah,al,lane,2,Wih2,Whh2,bih2,bhh2,20,15,16,24);
  else if (wv == 12) gatherA<4>(ah,al,lane,0,Wih3,Whh3,bih3,bhh3,30,20,24,32);
  else if (wv == 13) gatherA<4>(ah,al,lane,1,Wih3,Whh3,bih3,bhh3,30,20,24,32);
  else if (wv == 6)  gatherA<4>(ah,al,lane,2,Wih3,Whh3,bih3,bhh3,30,20,24,32);
  else if (wv == 3)  gatherA<4>(ah,al,lane,3,Wih3,Whh3,bih3,bhh3,30,20,24,32);
  else if (wv == 8)  gatherA<5>(ah,al,lane,0,Wih4,Whh4,bih4,bhh4,40,30,32,40);
  else if (wv == 9)  gatherA<5>(ah,al,lane,1,Wih4,Whh4,bih4,bhh4,40,30,32,40);
  else if (wv == 10) gatherA<5>(ah,al,lane,2,Wih4,Whh4,bih4,bhh4,40,30,32,40);
  else if (wv == 7)  gatherA<5>(ah,al,lane,3,Wih4,Whh4,bih4,bhh4,40,30,32,40);
  else if (wv == 11) gatherA<5>(ah,al,lane,4,Wih4,Whh4,bih4,bhh4,40,30,32,40);

  float cst[4] = {0,0,0,0};
  __syncthreads();

#pragma unroll 1
  for (int P = 0; P < TS + 4; ++P) {
    const int cur = P & 1, wp = cur ^ 1;
    const unsigned short* hp = S + cur*7680;
    unsigned short* wpp = S + wp*7680;
    float* scrW = scrA + wp*(32*44);

    if (wv <= 1) {                    // L1 m0/m1
      if (P <= TS-1) {
        const int mt = wv;
        const unsigned short* bp[2];
        bp[0] = hp + (up ? RH1 : 0) + n8;
        bp[1] = up ? (S + ZO + n8) : (hp + RH1 + 256 + n8);
        unsigned short* wr = wpp + RH1 + mt*256 + n8 + 4*up;
        doTile<2>(ah, al, bp, cst, wr, nullptr);
      }
    } else if (wv == 4 || wv == 5 || wv == 2) {   // L2 m0/m1/m2
      if (P >= 1 && P <= TS) {
        const int mt = (wv == 2) ? 2 : (wv - 4);
        const unsigned short* bp[3];
        bp[0] = hp + RH1 + (up ? 256 : 0) + n8;
        bp[1] = up ? (hp + RH2 + n8) : (S + ONEO + n8);
        bp[2] = hp + RH2 + (up ? 512 : 256) + n8;
        unsigned short* wr = wpp + RH2 + mt*256 + n8 + 4*up;
        doTile<3>(ah, al, bp, cst, wr, nullptr);
      }
    } else if (wv == 12 || wv == 13 || wv == 6 || wv == 3) {   // L3 m0..m3
      if (P >= 2 && P <= TS+1) {
        const int mt = (wv == 12) ? 0 : (wv == 13) ? 1 : (wv == 6) ? 2 : 3;
        const unsigned short* bp[4];
        bp[0] = hp + RH2 + (up ? 256 : 0) + n8;
        bp[1] = up ? (S + ONEO + n8) : (hp + RH2 + 512 + n8);
        bp[2] = hp + RH3 + (up ? 256 : 0) + n8;
        bp[3] = hp + RH3 + (up ? 768 : 512) + n8;
        unsigned short* wr = wpp + RH3 + mt*256 + n8 + 4*up;
        doTile<4>(ah, al, bp, cst, wr, nullptr);
      }
    } else if (wv >= 7 && wv <= 11) {   // L4 m0..m4
      if (P >= 3 && P <= TS+2) {
        const int mt = (wv == 7) ? 3 : (wv == 11) ? 4 : (wv - 8);
        const unsigned short* bp[5];
        bp[0] = hp + RH3 + (up ? 256 : 0) + n8;
        bp[1] = hp + RH3 + (up ? 768 : 512) + n8;
        bp[2] = up ? (hp + RH4 + n8) : (S + ONEO + n8);
        bp[3] = hp + RH4 + (up ? 512 : 256) + n8;
        bp[4] = hp + RH4 + (up ? 1024 : 768) + n8;
        unsigned short* wr = wpp + RH4 + mt*256 + n8 + 4*up;
        float* sc = scrW + n*44 + mt*8 + 4*up;
        doTile<5>(ah, al, bp, cst, wr, sc);
      }
    } else if (wv == 14) {   // y(P-4) + flush
      if (P >= 4) {
        const int ty = P - 4;
        const float* sp = scrA + cur*(32*44) + n*44 + up*20;
        float part = 0.0f;
#pragma unroll
        for (int q = 0; q < 5; ++q) {
          const float4 v = *(const float4*)(sp + 4*q);
          const float4 w = *(const float4*)(wlS + up*20 + 4*q);
          part = fmaf(v.x, w.x, fmaf(v.y, w.y, fmaf(v.z, w.z, fmaf(v.w, w.w, part))));
        }
        part += __shfl_xor(part, 32);
        if (lane < 32) obuf[n*68 + (ty & 63)] = part + wlS[40];
        if ((ty & 63) == 63) {
#pragma unroll
          for (int it = 0; it < 8; ++it) {
            const int row = it*4 + (lane >> 4), col = (lane & 15) << 2;
            const float4 v = *(const float4*)(obuf + row*68 + col);
            *(float4*)(out + (gb + row)*TS + (ty - 63) + col) = v;
          }
        }
      }
    } else {   // wv == 15: x(P+1) -> write parity SX
      if (P <= TS-2) {
        const int el = lane >> 1, half = lane & 1;
        const float* xa = x + (gb + el)*(TS*7) + (P + 1)*7 + (half << 2);
        const float v0 = xa[0], v1 = xa[1], v2 = xa[2];
        const float v3 = half ? 1.0f : xa[3];
        writeX(wpp, el, half, v0, v1, v2, v3);
      }
    }
    __syncthreads();
  }
}

extern "C" void kernel_launch(void* const* d_in, const int* in_sizes, int n_in,
                              void* d_out, int out_size, void* d_ws, size_t ws_size,
                              hipStream_t stream) {
  lstm_pipe16<<<dim3(8192/32), dim3(NT), 0, stream>>>(
      (const float*)d_in[0],
      (const float*)d_in[1],  (const float*)d_in[2],  (const float*)d_in[3],  (const float*)d_in[4],
      (const float*)d_in[5],  (const float*)d_in[6],  (const float*)d_in[7],  (const float*)d_in[8],
      (const float*)d_in[9],  (const float*)d_in[10], (const float*)d_in[11], (const float*)d_in[12],
      (const float*)d_in[13], (const float*)d_in[14], (const float*)d_in[15], (const float*)d_in[16],
      (const float*)d_in[17], (const float*)d_in[18],
      (float*)d_out);
}

// Round 14
// 785.759 us; speedup vs baseline: 1.0989x; 1.0989x over previous
//
#include <hip/hip_runtime.h>

// 4-layer LSTM (15/20/30/40), B=8192, T=512, fp32 in/out. MFMA split-bf16,
// layer-pipelined: period P runs L1@t=P, L2@P-1, L3@P-2, L4@P-3, y@P-4.
// 1024 threads = 16 waves, ONE tile per wave (14 tiles + y + x), 4 waves/SIMD,
// one barrier per period, h stored once per parity (shared slot maps).
// r14 = EXACT r7 restoration — the empirical optimum (786us PASS).
// Probes r11 (x prefetch), r12 (8-trans epilogue), r13 (3-acc MFMA split)
// each landed neutral-to-negative: the barrier-lockstep pipeline equilibrium
// (~3.7k cyc/period) re-absorbs component-level savings. Best-known config.

#define NT 1024
#define TS 512

typedef __attribute__((ext_vector_type(8)))  short short8v;
typedef __attribute__((ext_vector_type(16))) float f32x16;

// LDS (ushort units): 4 planes [parity(2) x hi/lo] of 3840:
//   region offsets within a plane: SX=0(1 slot) H1=256(2) H2=768(3)
//   H3=1536(4) H4=2560(5); slot = 256 ush = 32 elem x 8 k.
// plane(par,q) base = par*7680 + q*3840. Shared tail: ONE@15360 (0x3F80),
// Z@15616, and [19200,19712) zeros so ptr+3840 of ONE/Z reads zeros.
#define RH1 256
#define RH2 768
#define RH3 1536
#define RH4 2560
#define ONEO 15360
#define ZO   15616
#define STOTU 19712

__device__ __forceinline__ float fexp2(float x){ float r; asm("v_exp_f32 %0, %1" : "=v"(r) : "v"(x)); return r; }
__device__ __forceinline__ float frcp(float x){ float r; asm("v_rcp_f32 %0, %1" : "=v"(r) : "v"(x)); return r; }
#define LOG2E 1.4426950408889634f
__device__ __forceinline__ float sigm(float x)  { return frcp(1.0f + fexp2(-LOG2E * x)); }
__device__ __forceinline__ float tanhp(float x) { return 1.0f - 2.0f * frcp(1.0f + fexp2((2.0f*LOG2E) * x)); }

__device__ __forceinline__ unsigned cvtpk(float a, float b){
  unsigned r; asm("v_cvt_pk_bf16_f32 %0, %1, %2" : "=v"(r) : "v"(a), "v"(b)); return r;
}
__device__ __forceinline__ unsigned short bfr(float f){
  unsigned u = __float_as_uint(f);
  u += 0x7FFFu + ((u >> 16) & 1u);
  return (unsigned short)(u >> 16);
}
__device__ __forceinline__ float bfv(unsigned short s){
  return __uint_as_float(((unsigned)s) << 16);
}

// Gather one 32-row M-tile of split-bf16 A-fragments from global fp32.
// A-row m: gate g=m&3, unit u = 8*mt + 4*((m>>2)&1) + (m>>3) -> lane's C regs
// q=4r+g cover consecutive units u0t+4*up .. +3.
// k map: k<DIN: Wih; k==BIASK: bih+bhh; H0<=k<H0+DL: Whh[k-H0]; else 0.
template<int KT>
__device__ void gatherA(short8v (&ah)[5], short8v (&al)[5], int lane, int mt,
                        const float* Wih, const float* Whh,
                        const float* bih, const float* bhh,
                        int DL, int DIN, int BIASK, int H0) {
  const int upg = lane >> 5, rl = lane & 31;
  const int g = rl & 3;
  const int u = 8*mt + 4*((rl >> 2) & 1) + (rl >> 3);
#pragma unroll
  for (int kt = 0; kt < KT; ++kt) {
#pragma unroll
    for (int j = 0; j < 8; ++j) {
      const int k = kt*16 + upg*8 + j;
      float v = 0.0f;
      if (u < DL) {
        const int srow = g*DL + u;
        if (k < DIN)                      v = Wih[srow*DIN + k];
        else if (k == BIASK)              v = bih[srow] + bhh[srow];
        else if (k >= H0 && k < H0 + DL)  v = Whh[srow*DL + (k - H0)];
      }
      const unsigned short hi = bfr(v);
      const unsigned short lo = bfr(v - bfv(hi));
      ah[kt][j] = (short)hi;
      al[kt][j] = (short)lo;
    }
  }
}

// One tile: B-frag reads via precomputed slot pointers (lo plane = +3840),
// 3-term MFMA chain into one accumulator, lane-local cell update,
// b64 hi/lo h write at wr.
template<int KT>
__device__ __forceinline__ void doTile(
    const short8v (&ah)[5], const short8v (&al)[5],
    const unsigned short* const (&bp)[KT],
    float (&cst)[4], unsigned short* wr, float* scrp) {
  short8v Bh[KT], Bl[KT];
#pragma unroll
  for (int kt = 0; kt < KT; ++kt) {
    Bh[kt] = *(const short8v*)(bp[kt]);
    Bl[kt] = *(const short8v*)(bp[kt] + 3840);
  }
  f32x16 acc = {};
#pragma unroll
  for (int kt = 0; kt < KT; ++kt)
    acc = __builtin_amdgcn_mfma_f32_32x32x16_bf16(ah[kt], Bh[kt], acc, 0, 0, 0);
#pragma unroll
  for (int kt = 0; kt < KT; ++kt)
    acc = __builtin_amdgcn_mfma_f32_32x32x16_bf16(ah[kt], Bl[kt], acc, 0, 0, 0);
#pragma unroll
  for (int kt = 0; kt < KT; ++kt)
    acc = __builtin_amdgcn_mfma_f32_32x32x16_bf16(al[kt], Bh[kt], acc, 0, 0, 0);
  // C layout: col = lane&31 = element n, row = (q&3)+8*(q>>2)+4*up
  float h[4];
#pragma unroll
  for (int r = 0; r < 4; ++r) {
    const float ii = sigm(acc[4*r+0]);
    const float ff = sigm(acc[4*r+1]);
    const float g2 = tanhp(acc[4*r+2]);
    const float oo = sigm(acc[4*r+3]);
    cst[r] = fmaf(ff, cst[r], ii * g2);
    h[r] = oo * tanhp(cst[r]);
  }
  const unsigned pa = cvtpk(h[0], h[1]);
  const unsigned pb = cvtpk(h[2], h[3]);
  const float f0 = h[0] - __uint_as_float(pa << 16);
  const float f1 = h[1] - __uint_as_float(pa & 0xFFFF0000u);
  const float f2 = h[2] - __uint_as_float(pb << 16);
  const float f3 = h[3] - __uint_as_float(pb & 0xFFFF0000u);
  uint2 vh; vh.x = pa;            vh.y = pb;
  uint2 vl; vl.x = cvtpk(f0, f1); vl.y = cvtpk(f2, f3);
  *(uint2*)wr = vh;
  *(uint2*)(wr + 3840) = vl;
  if (scrp) *(float4*)scrp = make_float4(h[0], h[1], h[2], h[3]);
}

// x staging into SX slot: elem el, half -> k = half*4+j (half1: x4,x5,x6,1.0)
__device__ __forceinline__ void writeX(unsigned short* plane, int el, int half,
                                       float v0, float v1, float v2, float v3) {
  const unsigned pa = cvtpk(v0, v1), pb = cvtpk(v2, v3);
  const float f0 = v0 - __uint_as_float(pa << 16);
  const float f1 = v1 - __uint_as_float(pa & 0xFFFF0000u);
  const float f2 = v2 - __uint_as_float(pb << 16);
  const float f3 = v3 - __uint_as_float(pb & 0xFFFF0000u);
  uint2 vh; vh.x = pa;            vh.y = pb;
  uint2 vl; vl.x = cvtpk(f0, f1); vl.y = cvtpk(f2, f3);
  const int a = (el << 3) + (half << 2);
  *(uint2*)(plane + a) = vh;
  *(uint2*)(plane + a + 3840) = vl;
}

__global__ void __launch_bounds__(NT, 4)
lstm_pipe16(const float* __restrict__ x,
            const float* __restrict__ Wih1, const float* __restrict__ Whh1,
            const float* __restrict__ bih1, const float* __restrict__ bhh1,
            const float* __restrict__ Wih2, const float* __restrict__ Whh2,
            const float* __restrict__ bih2, const float* __restrict__ bhh2,
            const float* __restrict__ Wih3, const float* __restrict__ Whh3,
            const float* __restrict__ bih3, const float* __restrict__ bhh3,
            const float* __restrict__ Wih4, const float* __restrict__ Whh4,
            const float* __restrict__ bih4, const float* __restrict__ bhh4,
            const float* __restrict__ Wl, const float* __restrict__ bl,
            float* __restrict__ out) {
  __shared__ __align__(16) unsigned short S[STOTU];
  __shared__ __align__(16) float scrA[2*32*44];
  __shared__ __align__(16) float obuf[32*68];
  __shared__ float wlS[41];

  const int tid  = threadIdx.x;
  const int wv   = tid >> 6, lane = tid & 63;
  const int n    = lane & 31, up = lane >> 5;
  const int n8   = n << 3;
  const long gb  = (long)blockIdx.x * 32;

  for (int i = tid; i < STOTU/2; i += NT) ((unsigned*)S)[i] = 0u;
  if (tid < 41) wlS[tid] = (tid < 40) ? Wl[tid] : bl[0];
  __syncthreads();
  if (tid < 256) S[ONEO + tid] = 0x3F80;   // shared ones slot (hi only)
  // x(0) -> parity 0 SX (wv15)
  if (wv == 15) {
    const int el = lane >> 1, half = lane & 1;
    const float* xa = x + (gb + el)*(TS*7) + (half << 2);
    writeX(S + 0, el, half, xa[0], xa[1], xa[2], half ? 1.0f : xa[3]);
  }

  // ---- one-time A-frag gather; role table (SIMD-balanced by wv&3) ----
  // wv: 0=L1m0 1=L1m1 2=L2m2 3=L3m3 4=L2m0 5=L2m1 6=L3m2 7=L4m3
  //     8=L4m0 9=L4m1 10=L4m2 11=L4m4 12=L3m0 13=L3m1 14=y 15=x
  short8v ah[5], al[5];
  if      (wv == 0)  gatherA<2>(ah,al,lane,0,Wih1,Whh1,bih1,bhh1,15,7,7,8);
  else if (wv == 1)  gatherA<2>(ah,al,lane,1,Wih1,Whh1,bih1,bhh1,15,7,7,8);
  else if (wv == 4)  gatherA<3>(ah,al,lane,0,Wih2,Whh2,bih2,bhh2,20,15,16,24);
  else if (wv == 5)  gatherA<3>(ah,al,lane,1,Wih2,Whh2,bih2,bhh2,20,15,16,24);
  else if (wv == 2)  gatherA<3>(ah,al,lane,2,Wih2,Whh2,bih2,bhh2,20,15,16,24);
  else if (wv == 12) gatherA<4>(ah,al,lane,0,Wih3,Whh3,bih3,bhh3,30,20,24,32);
  else if (wv == 13) gatherA<4>(ah,al,lane,1,Wih3,Whh3,bih3,bhh3,30,20,24,32);
  else if (wv == 6)  gatherA<4>(ah,al,lane,2,Wih3,Whh3,bih3,bhh3,30,20,24,32);
  else if (wv == 3)  gatherA<4>(ah,al,lane,3,Wih3,Whh3,bih3,bhh3,30,20,24,32);
  else if (wv == 8)  gatherA<5>(ah,al,lane,0,Wih4,Whh4,bih4,bhh4,40,30,32,40);
  else if (wv == 9)  gatherA<5>(ah,al,lane,1,Wih4,Whh4,bih4,bhh4,40,30,32,40);
  else if (wv == 10) gatherA<5>(ah,al,lane,2,Wih4,Whh4,bih4,bhh4,40,30,32,40);
  else if (wv == 7)  gatherA<5>(ah,al,lane,3,Wih4,Whh4,bih4,bhh4,40,30,32,40);
  else if (wv == 11) gatherA<5>(ah,al,lane,4,Wih4,Whh4,bih4,bhh4,40,30,32,40);

  float cst[4] = {0,0,0,0};
  __syncthreads();

#pragma unroll 1
  for (int P = 0; P < TS + 4; ++P) {
    const int cur = P & 1, wp = cur ^ 1;
    const unsigned short* hp = S + cur*7680;
    unsigned short* wpp = S + wp*7680;
    float* scrW = scrA + wp*(32*44);

    if (wv <= 1) {                    // L1 m0/m1
      if (P <= TS-1) {
        const int mt = wv;
        const unsigned short* bp[2];
        bp[0] = hp + (up ? RH1 : 0) + n8;
        bp[1] = up ? (S + ZO + n8) : (hp + RH1 + 256 + n8);
        unsigned short* wr = wpp + RH1 + mt*256 + n8 + 4*up;
        doTile<2>(ah, al, bp, cst, wr, nullptr);
      }
    } else if (wv == 4 || wv == 5 || wv == 2) {   // L2 m0/m1/m2
      if (P >= 1 && P <= TS) {
        const int mt = (wv == 2) ? 2 : (wv - 4);
        const unsigned short* bp[3];
        bp[0] = hp + RH1 + (up ? 256 : 0) + n8;
        bp[1] = up ? (hp + RH2 + n8) : (S + ONEO + n8);
        bp[2] = hp + RH2 + (up ? 512 : 256) + n8;
        unsigned short* wr = wpp + RH2 + mt*256 + n8 + 4*up;
        doTile<3>(ah, al, bp, cst, wr, nullptr);
      }
    } else if (wv == 12 || wv == 13 || wv == 6 || wv == 3) {   // L3 m0..m3
      if (P >= 2 && P <= TS+1) {
        const int mt = (wv == 12) ? 0 : (wv == 13) ? 1 : (wv == 6) ? 2 : 3;
        const unsigned short* bp[4];
        bp[0] = hp + RH2 + (up ? 256 : 0) + n8;
        bp[1] = up ? (S + ONEO + n8) : (hp + RH2 + 512 + n8);
        bp[2] = hp + RH3 + (up ? 256 : 0) + n8;
        bp[3] = hp + RH3 + (up ? 768 : 512) + n8;
        unsigned short* wr = wpp + RH3 + mt*256 + n8 + 4*up;
        doTile<4>(ah, al, bp, cst, wr, nullptr);
      }
    } else if (wv >= 7 && wv <= 11) {   // L4 m0..m4
      if (P >= 3 && P <= TS+2) {
        const int mt = (wv == 7) ? 3 : (wv == 11) ? 4 : (wv - 8);
        const unsigned short* bp[5];
        bp[0] = hp + RH3 + (up ? 256 : 0) + n8;
        bp[1] = hp + RH3 + (up ? 768 : 512) + n8;
        bp[2] = up ? (hp + RH4 + n8) : (S + ONEO + n8);
        bp[3] = hp + RH4 + (up ? 512 : 256) + n8;
        bp[4] = hp + RH4 + (up ? 1024 : 768) + n8;
        unsigned short* wr = wpp + RH4 + mt*256 + n8 + 4*up;
        float* sc = scrW + n*44 + mt*8 + 4*up;
        doTile<5>(ah, al, bp, cst, wr, sc);
      }
    } else if (wv == 14) {   // y(P-4) + flush
      if (P >= 4) {
        const int ty = P - 4;
        const float* sp = scrA + cur*(32*44) + n*44 + up*20;
        float part = 0.0f;
#pragma unroll
        for (int q = 0; q < 5; ++q) {
          const float4 v = *(const float4*)(sp + 4*q);
          const float4 w = *(const float4*)(wlS + up*20 + 4*q);
          part = fmaf(v.x, w.x, fmaf(v.y, w.y, fmaf(v.z, w.z, fmaf(v.w, w.w, part))));
        }
        part += __shfl_xor(part, 32);
        if (lane < 32) obuf[n*68 + (ty & 63)] = part + wlS[40];
        if ((ty & 63) == 63) {
#pragma unroll
          for (int it = 0; it < 8; ++it) {
            const int row = it*4 + (lane >> 4), col = (lane & 15) << 2;
            const float4 v = *(const float4*)(obuf + row*68 + col);
            *(float4*)(out + (gb + row)*TS + (ty - 63) + col) = v;
          }
        }
      }
    } else {   // wv == 15: x(P+1) -> write parity SX
      if (P <= TS-2) {
        const int el = lane >> 1, half = lane & 1;
        const float* xa = x + (gb + el)*(TS*7) + (P + 1)*7 + (half << 2);
        const float v0 = xa[0], v1 = xa[1], v2 = xa[2];
        const float v3 = half ? 1.0f : xa[3];
        writeX(wpp, el, half, v0, v1, v2, v3);
      }
    }
    __syncthreads();
  }
}

extern "C" void kernel_launch(void* const* d_in, const int* in_sizes, int n_in,
                              void* d_out, int out_size, void* d_ws, size_t ws_size,
                              hipStream_t stream) {
  lstm_pipe16<<<dim3(8192/32), dim3(NT), 0, stream>>>(
      (const float*)d_in[0],
      (const float*)d_in[1],  (const float*)d_in[2],  (const float*)d_in[3],  (const float*)d_in[4],
      (const float*)d_in[5],  (const float*)d_in[6],  (const float*)d_in[7],  (const float*)d_in[8],
      (const float*)d_in[9],  (const float*)d_in[10], (const float*)d_in[11], (const float*)d_in[12],
      (const float*)d_in[13], (const float*)d_in[14], (const float*)d_in[15], (const float*)d_in[16],
      (const float*)d_in[17], (const float*)d_in[18],
      (float*)d_out);
}